// Round 6
// baseline (181.346 us; speedup 1.0000x reference)
//
#include <hip/hip_runtime.h>
#include <math.h>

typedef float f32x4 __attribute__((ext_vector_type(4)));
typedef float f32x2 __attribute__((ext_vector_type(2)));
typedef int   i32x4 __attribute__((ext_vector_type(4)));

// RBF constants: means = linspace(exp(-5), 1, 128); beta = (2/128*(1-exp(-5)))^-2
#define RBF_START 0.006737946999085467f
#define RBF_H     (0.993262053000915f / 127.0f)
#define RBF_INVH  (127.0f / 0.993262053000915f)
#define RBF_BETA  (1.0f / ((2.0f/128.0f*0.993262053000915f) * (2.0f/128.0f*0.993262053000915f)))
#define KN 256          // knots: KN+1 samples of e in [0,1]; lerp err ~1e-6 on bias

// ---------------- kernel A: padding mask (blocks 0..2047) + bias-table build (blocks 2048..2304) ----------------
__global__ __launch_bounds__(256) void prep_kernel(
    const float* __restrict__ nf, int* __restrict__ mask,
    const float* __restrict__ w1, const float* __restrict__ b1,
    const float* __restrict__ w2, const float* __restrict__ b2,
    float* __restrict__ tableG) {
  int g = blockIdx.x, t = threadIdx.x;
  if (g < 2048) {
    const float* p = nf + (size_t)g * 768;
    bool nz = (p[t] != 0.f) || (p[t + 256] != 0.f) || (p[t + 512] != 0.f);
    __shared__ int wany[4];
    unsigned long long bal = __ballot(nz);
    if ((t & 63) == 0) wany[t >> 6] = (bal != 0ull);
    __syncthreads();
    if (t == 0) mask[g] = (wany[0] | wany[1] | wany[2] | wany[3]) ? 0 : 1;
  } else {
    int knot = g - 2048;                       // 0..256
    float e = (float)knot * (1.0f / (float)KN);
    __shared__ float ef_s[128];
    __shared__ float hid_s[128];
    if (t < 128) {
      float mu = fmaf((float)t, RBF_H, RBF_START);
      float diff = e - mu;
      ef_s[t] = __expf(-RBF_BETA * diff * diff);
    }
    __syncthreads();
    if (t < 128) {
      float s = b1[t];
      for (int k = 0; k < 128; k++) s = fmaf(ef_s[k], w1[k * 128 + t], s);
      hid_s[t] = 0.5f * s * (1.0f + erff(s * 0.70710678118654752f));  // exact GELU
    }
    __syncthreads();
    int h = t >> 3, seg = t & 7;               // 32 heads x 8 segments
    float s = 0.f;
    const float* hp = hid_s + seg * 16;
    const float* wp = w2 + (seg * 16) * 32 + h;
#pragma unroll
    for (int m = 0; m < 16; m++) s = fmaf(hp[m], wp[m * 32], s);
    s += __shfl_xor(s, 1);
    s += __shfl_xor(s, 2);
    s += __shfl_xor(s, 4);
    if (seg == 0) tableG[h * (KN + 1) + knot] = s + b2[h];
  }
}

// ---------------- kernel B1: distances -> e, delta_pos, banded column sums ----------------
// Block = 256 thr = one (b,i); thread t <-> key node j. Tiny LDS -> high occupancy.
__global__ __launch_bounds__(256) void e_kernel(
    const float* __restrict__ pos, const int* __restrict__ mask,
    float* __restrict__ ebuf, float* __restrict__ out2, float* __restrict__ part) {
  __shared__ float part_s[128];
  int t = threadIdx.x, g = blockIdx.x;
  int b = g >> 8, i = g & 255;
  if (t < 128) part_s[t] = 0.f;
  __syncthreads();

  int j = t;
  const float* pb = pos + b * 768;
  float pix = pb[i * 3 + 0], piy = pb[i * 3 + 1], piz = pb[i * 3 + 2];
  float dx = pix - pb[j * 3 + 0];
  float dy = piy - pb[j * 3 + 1];
  float dz = piz - pb[j * 3 + 2];
  float r2 = dx * dx + dy * dy + dz * dz;
  float d = (r2 > 0.f) ? sqrtf(r2) : 0.f;
  float e = __expf(-d);                        // ALPHA=1, CUT_LO=0
  size_t base2 = ((size_t)g * 256 + (size_t)j) * 3;
  out2[base2 + 0] = dx; out2[base2 + 1] = dy; out2[base2 + 2] = dz;
  ebuf[(size_t)g * 256 + j] = e;

  bool pad = mask[b * 256 + j] != 0;
  if (!pad) {
    int kc = (int)rintf((e - RBF_START) * RBF_INVH);
    kc = min(max(kc, 0), 127);
    int kb = kc - 8;                           // exp(-beta*dk^2) < 8e-8 for |dk| >= 8
#pragma unroll
    for (int o = 0; o < 16; o++) {
      int k = kb + o;
      if (k >= 0 && k < 128) {
        float mu = fmaf((float)k, RBF_H, RBF_START);
        float diff = e - mu;
        atomicAdd(&part_s[k], __expf(-RBF_BETA * diff * diff));
      }
    }
  }
  __syncthreads();
  if (t < 128) part[(size_t)g * 128 + t] = part_s[t];
}

// ---------------- kernel B2: pure streaming expand  out0[b][h][i][j] = lerp(T[h], e[b,i,j]) ----------------
// Grid 1024 = (b, h, i-quarter). Each block writes 64 KB perfectly sequential within one
// contiguous 256 KB head plane; stores spread through kernel life, unroll-4 ILP, NT.
__global__ __launch_bounds__(256, 4) void bias_kernel(
    const float* __restrict__ tableG, const int* __restrict__ mask,
    const float* __restrict__ ebuf, float* __restrict__ out0) {
  __shared__ f32x2 Tp[256];                 // Tp[k] = {T[k], T[k+1]}: one ds_read_b64 per lerp

  int t = threadIdx.x, bid = blockIdx.x;
  int b = bid >> 7, h = (bid >> 2) & 31, qi = bid & 3;

  {
    float lo = tableG[h * (KN + 1) + t];
    float hi = tableG[h * (KN + 1) + t + 1];   // t+1 <= 256, in row
    Tp[t] = (f32x2){lo, hi};
  }
  int w = t >> 6, l = t & 63;                  // wave w handles row (4*iter + w), j = 4l..4l+3
  i32x4 m4 = *(const i32x4*)&mask[b * 256 + l * 4];
  __syncthreads();

  size_t ebase = ((size_t)(b * 256 + qi * 64 + w)) * 256 + (size_t)(l * 4);
  size_t obase = ((size_t)((b * 32 + h) * 256 + qi * 64 + w)) * 256 + (size_t)(l * 4);

#pragma unroll 4
  for (int ii = 0; ii < 16; ii++) {
    f32x4 e4 = *(const f32x4*)&ebuf[ebase + (size_t)ii * 1024];
    f32x4 o;
#pragma unroll
    for (int r = 0; r < 4; r++) {
      float u = e4[r] * (float)KN;
      int i0 = (int)u; i0 = min(i0, KN - 1);
      float fr = u - (float)i0;
      f32x2 tp = Tp[i0];
      float v = fmaf(fr, tp[1] - tp[0], tp[0]);
      o[r] = m4[r] ? -1e20f : v;
    }
    __builtin_nontemporal_store(o, (f32x4*)&out0[obase + (size_t)ii * 1024]);
  }
}

// ---------------- kernel C: merge_edge_features = part @ ew + eb ----------------
__global__ __launch_bounds__(256) void merge_kernel(const float* __restrict__ part,
                                                    const float* __restrict__ ew,
                                                    const float* __restrict__ eb,
                                                    float* __restrict__ out1) {
  __shared__ float s_s[8][128];
  int t = threadIdx.x;
  int r0 = blockIdx.x * 8;
  for (int idx = t; idx < 1024; idx += 256) {
    int row = idx >> 7, k = idx & 127;
    s_s[row][k] = part[(size_t)(r0 + row) * 128 + k];
  }
  __syncthreads();
  float acc[3][8];
#pragma unroll
  for (int c = 0; c < 3; c++)
#pragma unroll
    for (int r = 0; r < 8; r++) acc[c][r] = 0.f;
  for (int k = 0; k < 128; k++) {
    float w0 = ew[k * 768 + t];
    float w1v = ew[k * 768 + t + 256];
    float w2v = ew[k * 768 + t + 512];
#pragma unroll
    for (int r = 0; r < 8; r++) {
      float s = s_s[r][k];
      acc[0][r] += s * w0;
      acc[1][r] += s * w1v;
      acc[2][r] += s * w2v;
    }
  }
#pragma unroll
  for (int c = 0; c < 3; c++) {
    float ebv = eb[c * 256 + t];
#pragma unroll
    for (int r = 0; r < 8; r++)
      out1[(size_t)(r0 + r) * 768 + c * 256 + t] = acc[c][r] + ebv;
  }
}

// ---------------- launch ----------------
extern "C" void kernel_launch(void* const* d_in, const int* in_sizes, int n_in,
                              void* d_out, int out_size, void* d_ws, size_t ws_size,
                              hipStream_t stream) {
    const float* nf    = (const float*)d_in[0];
    const float* pos   = (const float*)d_in[1];
    const float* w1    = (const float*)d_in[4];
    const float* b1    = (const float*)d_in[5];
    const float* w2    = (const float*)d_in[6];
    const float* b2    = (const float*)d_in[7];
    const float* ew    = (const float*)d_in[8];
    const float* eb    = (const float*)d_in[9];

    float* out0 = (float*)d_out;                         // [8,32,256,256]
    float* out1 = out0 + (size_t)8 * 32 * 256 * 256;     // [8,256,768]
    float* out2 = out1 + (size_t)8 * 256 * 768;          // [8,256,256,3]

    char* ws = (char*)d_ws;
    int*    mask   = (int*)ws;                           // 8 KB
    float*  tableG = (float*)(ws + 8192);                // 32896 B
    float*  part   = (float*)(ws + 49152);               // 2048*128*4 = 1 MB
    float*  ebuf   = (float*)(ws + 49152 + 1048576);     // 2048*256*4 = 2 MB

    hipLaunchKernelGGL(prep_kernel, dim3(2305), dim3(256), 0, stream,
                       nf, mask, w1, b1, w2, b2, tableG);
    hipLaunchKernelGGL(e_kernel,    dim3(2048), dim3(256), 0, stream,
                       pos, mask, ebuf, out2, part);
    hipLaunchKernelGGL(bias_kernel, dim3(1024), dim3(256), 0, stream,
                       tableG, mask, ebuf, out0);
    hipLaunchKernelGGL(merge_kernel, dim3(256), dim3(256), 0, stream, part, ew, eb, out1);
}